// Round 8
// baseline (1501.205 us; speedup 1.0000x reference)
//
#include <hip/hip_runtime.h>
#include <hip/hip_bf16.h>

#define BNC 0.99950037f   // 1/sqrt(1+1e-3), BN eval scale factor
#define GH 400
#define GW 352

typedef __bf16 bf16_t;
typedef __bf16 bf16x8 __attribute__((ext_vector_type(8)));
typedef float f32x4 __attribute__((ext_vector_type(4)));

// ---------------------------------------------------------------------------
// Winner grid: last voxel index wins for duplicate cells (matches np fancy-set)
// ---------------------------------------------------------------------------
__global__ void k_winner(const int* __restrict__ coors, int* __restrict__ winner, int N) {
    int i = blockIdx.x * 256 + threadIdx.x;
    if (i >= N) return;
    int d = coors[i*4+1], h = coors[i*4+2], w = coors[i*4+3];
    atomicMax(&winner[(d*GH + h)*GW + w], i);
}

// ---------------------------------------------------------------------------
// Weight transpose for conv1/gather: OIDHW -> [tap][ci4][co][4]
// ---------------------------------------------------------------------------
__global__ void k_tr_w(const float* __restrict__ w, float* __restrict__ wt, int CI, int CO) {
    int idx = blockIdx.x * 256 + threadIdx.x;
    int total = 27 * CI * CO;
    if (idx >= total) return;
    int j   = idx & 3;
    int t1  = idx >> 2;
    int co  = t1 % CO;
    int t2  = t1 / CO;
    int ci4 = t2 % (CI/4);
    int tap = t2 / (CI/4);
    int ci  = ci4*4 + j;
    wt[idx] = w[(co*CI + ci)*27 + tap];
}

// Linear-layer weight transpose: wl[u][c] -> WT[c][u]
__global__ void k_tr_lin(const float* __restrict__ wl, float* __restrict__ WT) {
    int idx = blockIdx.x * 256 + threadIdx.x;
    if (idx >= 16384) return;
    int u = idx & 127, c = idx >> 7;
    WT[c*128 + u] = wl[u*128 + c];
}

// Input-activation table for convs: [0:64) gc1*BNC, [64:128) bc1,
// [128:192) 1.0, [192:256) 0.0 (identity block for conv3)
__global__ void k_prep(const float* __restrict__ g, const float* __restrict__ b,
                       float* __restrict__ out) {
    int i = threadIdx.x;
    if (i < 64)       out[i] = g[i] * BNC;
    else if (i < 128) out[i] = b[i-64];
    else if (i < 192) out[i] = 1.f;
    else              out[i] = 0.f;
}

// ---------------------------------------------------------------------------
// Pack 64x64x27 conv weights (OIDHW fp32) into MFMA B-fragment order, split
// into hi/lo bf16. Frag index fb = (s*4 + ct)*64 + lane, s = tap*2 + h.
// Lane l of B[k][n]: n(co) = ct*16 + (l&15), k(ci) = h*32 + (l>>4)*8 + j.
// ---------------------------------------------------------------------------
__global__ void k_packw(const float* __restrict__ w, bf16_t* __restrict__ wh,
                        bf16_t* __restrict__ wlo) {
    int i = blockIdx.x * 256 + threadIdx.x;    // over 54*4*64 = 13824 frag-lanes
    if (i >= 13824) return;
    int lane = i & 63, ct = (i >> 6) & 3, s = i >> 8;
    int tap = s >> 1, h = s & 1;
    int kg = lane >> 4, wl = lane & 15;
    int co = ct*16 + wl;
    #pragma unroll
    for (int j = 0; j < 8; ++j) {
        int ci = h*32 + kg*8 + j;
        float v = w[(co*64 + ci)*27 + tap];
        bf16_t hi = (bf16_t)v;
        wh[(long)i*8 + j]  = hi;
        wlo[(long)i*8 + j] = (bf16_t)(v - (float)hi);
    }
}

// ---------------------------------------------------------------------------
// VFE: one block (128 thr) per voxel. Agg-split form (unchanged from r7).
// ---------------------------------------------------------------------------
__global__ __launch_bounds__(128) void k_vfe(
    const float* __restrict__ feats, const int* __restrict__ nvox,
    const float* __restrict__ w1, const float* __restrict__ g1g, const float* __restrict__ b1g,
    const float* __restrict__ w2g, const float* __restrict__ g2g, const float* __restrict__ b2g,
    const float* __restrict__ WT, const float* __restrict__ glg, const float* __restrict__ blg,
    float* __restrict__ voxelwise)
{
    __shared__ float F[35*8];
    __shared__ float W1s[16*8];
    __shared__ float SG1[16], SB1[16];
    __shared__ float X1[35*20];
    __shared__ float X2[35*68];
    __shared__ float RED[8*128];
    __shared__ float AGG1[16];
    __shared__ float AGG2[64];
    __shared__ float Y2B[64];
    __shared__ float YB[128];
    __shared__ float MEANS[3];

    int tid = threadIdx.x;
    int vox = blockIdx.x;
    int nv  = nvox[vox];

    const float* fsrc = feats + (long)vox * 140;
    for (int idx = tid; idx < 140; idx += 128) { int t = idx>>2, c = idx&3; F[t*8+c] = fsrc[idx]; }
    if (tid < 35) F[tid*8+7] = 0.f;
    if (tid < 112) { int u = tid/7, c = tid - u*7; W1s[u*8+c] = w1[tid]; }
    if (tid < 16)  { W1s[tid*8+7] = 0.f; SG1[tid] = g1g[tid]*BNC; SB1[tid] = b1g[tid]; }
    __syncthreads();

    if (tid < 3) {
        float s = 0.f;
        for (int t = 0; t < 35; ++t) s += F[t*8 + tid];
        MEANS[tid] = s / (float)nv;
    }
    __syncthreads();
    for (int idx = tid; idx < 105; idx += 128) { int t = idx/3, c = idx - t*3; F[t*8+4+c] = F[t*8+c] - MEANS[c]; }
    __syncthreads();

    {
        const float4* Ff4  = (const float4*)F;
        const float4* W1f4 = (const float4*)W1s;
        for (int idx = tid; idx < 560; idx += 128) {
            int t = idx >> 4, u = idx & 15;
            float4 a0 = Ff4[t*2], a1 = Ff4[t*2+1];
            float4 b0 = W1f4[u*2], b1v = W1f4[u*2+1];
            float a = a0.x*b0.x + a0.y*b0.y + a0.z*b0.z + a0.w*b0.w
                    + a1.x*b1v.x + a1.y*b1v.y + a1.z*b1v.z + a1.w*b1v.w;
            X1[t*20+u] = fmaxf(a*SG1[u] + SB1[u], 0.f);
        }
    }
    __syncthreads();
    if (tid < 16) {
        float m = 0.f;
        for (int t = 0; t < 35; ++t) m = fmaxf(m, X1[t*20+tid]);
        AGG1[tid] = m;
    }
    __syncthreads();
    if (tid < 64) {
        const float4* wsrc = (const float4*)(w2g + tid*32 + 16);
        const float4* A1f4 = (const float4*)AGG1;
        float a = 0.f;
        #pragma unroll
        for (int q = 0; q < 4; ++q) {
            float4 w4 = wsrc[q], x4 = A1f4[q];
            a += x4.x*w4.x + x4.y*w4.y + x4.z*w4.z + x4.w*w4.w;
        }
        Y2B[tid] = a;
    }
    __syncthreads();

    {
        int u = tid & 63, tg = tid >> 6;
        float w2r[16];
        const float4* wsrc = (const float4*)(w2g + u*32);
        #pragma unroll
        for (int q = 0; q < 4; ++q) {
            float4 w4 = wsrc[q];
            w2r[q*4] = w4.x; w2r[q*4+1] = w4.y; w2r[q*4+2] = w4.z; w2r[q*4+3] = w4.w;
        }
        float su = g2g[u]*BNC, bu = b2g[u];
        float yb2 = Y2B[u];
        float lm = (nv < 35) ? fmaxf(bu, 0.f) : 0.f;
        for (int t = tg; t < nv; t += 2) {
            const float4* xr = (const float4*)(X1 + t*20);
            float a = yb2;
            #pragma unroll
            for (int q = 0; q < 4; ++q) {
                float4 x4 = xr[q];
                a += x4.x*w2r[q*4] + x4.y*w2r[q*4+1] + x4.z*w2r[q*4+2] + x4.w*w2r[q*4+3];
            }
            float h = fmaxf(a*su + bu, 0.f);
            X2[t*68 + u] = h;
            lm = fmaxf(lm, h);
        }
        RED[tg*64 + u] = lm;
    }
    __syncthreads();
    if (tid < 64) AGG2[tid] = fmaxf(RED[tid], RED[64+tid]);
    __syncthreads();
    {
        float a = 0.f;
        for (int c = 0; c < 64; ++c) a = fmaf(AGG2[c], WT[(64 + c)*128 + tid], a);
        YB[tid] = a;
    }
    __syncthreads();

    {
        int ug = tid & 15, tg4 = tid >> 4;
        int u0 = ug * 8;
        int kmax = (nv > tg4) ? ((nv - tg4 + 7) >> 3) : 0;
        float acc[5][8];
        #pragma unroll
        for (int k = 0; k < 5; ++k)
            #pragma unroll
            for (int j = 0; j < 8; ++j) acc[k][j] = 0.f;

        const float4* X2f4 = (const float4*)X2;
        const float4* WTf4 = (const float4*)WT;
        for (int c4 = 0; c4 < 16; ++c4) {
            float4 wv[8];
            #pragma unroll
            for (int cc = 0; cc < 4; ++cc) {
                wv[cc*2]   = WTf4[(c4*4+cc)*32 + ug*2];
                wv[cc*2+1] = WTf4[(c4*4+cc)*32 + ug*2 + 1];
            }
            #pragma unroll
            for (int k = 0; k < 5; ++k) {
                if (k < kmax) {
                    int t = tg4 + (k << 3);
                    float4 x4 = X2f4[t*17 + c4];
                    #pragma unroll
                    for (int cc = 0; cc < 4; ++cc) {
                        float xs = (cc == 0) ? x4.x : (cc == 1) ? x4.y : (cc == 2) ? x4.z : x4.w;
                        acc[k][0] = fmaf(xs, wv[cc*2].x,   acc[k][0]);
                        acc[k][1] = fmaf(xs, wv[cc*2].y,   acc[k][1]);
                        acc[k][2] = fmaf(xs, wv[cc*2].z,   acc[k][2]);
                        acc[k][3] = fmaf(xs, wv[cc*2].w,   acc[k][3]);
                        acc[k][4] = fmaf(xs, wv[cc*2+1].x, acc[k][4]);
                        acc[k][5] = fmaf(xs, wv[cc*2+1].y, acc[k][5]);
                        acc[k][6] = fmaf(xs, wv[cc*2+1].z, acc[k][6]);
                        acc[k][7] = fmaf(xs, wv[cc*2+1].w, acc[k][7]);
                    }
                }
            }
        }
        float4 g0 = *(const float4*)(glg + u0), g1v = *(const float4*)(glg + u0 + 4);
        float4 b0 = *(const float4*)(blg + u0), b1v = *(const float4*)(blg + u0 + 4);
        float4 y0 = *(const float4*)(YB + u0),  y1v = *(const float4*)(YB + u0 + 4);
        float sg[8] = {g0.x*BNC, g0.y*BNC, g0.z*BNC, g0.w*BNC,
                       g1v.x*BNC, g1v.y*BNC, g1v.z*BNC, g1v.w*BNC};
        float sb[8] = {b0.x, b0.y, b0.z, b0.w, b1v.x, b1v.y, b1v.z, b1v.w};
        float yv[8] = {y0.x, y0.y, y0.z, y0.w, y1v.x, y1v.y, y1v.z, y1v.w};
        float m[8];
        #pragma unroll
        for (int j = 0; j < 8; ++j) m[j] = 0.f;
        #pragma unroll
        for (int k = 0; k < 5; ++k) {
            if (k < kmax) {
                #pragma unroll
                for (int j = 0; j < 8; ++j)
                    m[j] = fmaxf(m[j], fmaxf((acc[k][j] + yv[j])*sg[j] + sb[j], 0.f));
            }
        }
        #pragma unroll
        for (int j = 0; j < 8; ++j) RED[tg4*128 + u0 + j] = m[j];
    }
    __syncthreads();
    {
        float m = RED[tid];
        #pragma unroll
        for (int r = 1; r < 8; ++r) m = fmaxf(m, RED[r*128 + tid]);
        voxelwise[(long)vox*128 + tid] = m;
    }
}

// ---------------------------------------------------------------------------
// conv1 as GATHER (atomic-free): out[do,oh,w,co] = sum over taps of
// voxw[winner(2do+kd-1, oh+kh-1, w+kw-1)] . W1col[tap][:,co], zero if no
// winner. Writes every cell of its rows -> replaces accS memset entirely.
// Winner window staged in LDS (9 rows x 34 ints); feature reads are
// wave-broadcast; weight reads identical L2-hot pattern as old scatter.
// ---------------------------------------------------------------------------
__global__ __launch_bounds__(256) void k_gat1(
    const float4* __restrict__ voxf4, const int* __restrict__ winner,
    const float4* __restrict__ Wt1, float* __restrict__ accS,
    int h_lo, int AR)
{
    int r  = blockIdx.y;               // row within strip accumulator
    int oh = h_lo + r;
    if ((unsigned)oh >= (unsigned)GH) return;   // conv2 never reads such rows
    int doo = blockIdx.z;
    int w0  = blockIdx.x * 32;

    __shared__ int sWin[3][3][36];
    int t = threadIdx.x;
    for (int idx = t; idx < 306; idx += 256) {
        int x = idx % 34, q = idx / 34;
        int kd = q / 3, kh = q - kd*3;
        int dp = doo*2 + kd - 1;
        int hp = oh + kh - 1;
        int wp = w0 - 1 + x;
        int v = -1;
        if ((unsigned)dp < 10u && (unsigned)hp < (unsigned)GH && (unsigned)wp < (unsigned)GW)
            v = winner[(dp*GH + hp)*GW + wp];
        sWin[kd][kh][x] = v;
    }
    __syncthreads();

    int co = t & 63, wq = t >> 6;      // wave handles 8 consecutive w-cells
    float acc[8];
    #pragma unroll
    for (int i = 0; i < 8; ++i) acc[i] = 0.f;

    for (int kd = 0; kd < 3; ++kd) {
        for (int kh = 0; kh < 3; ++kh) {
            #pragma unroll
            for (int kw = 0; kw < 3; ++kw) {
                const float4* wbase = Wt1 + (long)(kd*9 + kh*3 + kw)*2048 + co;
                #pragma unroll
                for (int i = 0; i < 8; ++i) {
                    int widx = sWin[kd][kh][wq*8 + i + kw];   // wave-uniform
                    if (widx >= 0) {
                        const float4* f = voxf4 + (long)widx*32;
                        float a = 0.f;
                        for (int c4 = 0; c4 < 32; ++c4) {
                            float4 wv = wbase[c4*64];
                            float4 fv = f[c4];
                            a += fv.x*wv.x + fv.y*wv.y + fv.z*wv.z + fv.w*wv.w;
                        }
                        acc[i] += a;
                    }
                }
            }
        }
    }

    long rowb = ((long)doo*AR + r)*GW + w0;
    #pragma unroll
    for (int i = 0; i < 8; ++i)
        accS[(rowb + wq*8 + i)*64 + co] = acc[i];
}

// ---------------------------------------------------------------------------
// Dense conv3d via MFMA 16x16x32 bf16, 3-product hi/lo split (unchanged).
// ---------------------------------------------------------------------------
__global__ __launch_bounds__(256) void k_convm(
    const float* __restrict__ src, int src_h0, long src_dpitch,
    float* __restrict__ dst, int dst_h0, long sC, long sD, long sH, long sW,
    const bf16_t* __restrict__ wph, const bf16_t* __restrict__ wpl,
    const float* __restrict__ gact,
    const float* __restrict__ gout, const float* __restrict__ bout,
    int D_in, int d_stride, int d_pad, int y0)
{
    int oh = y0 + (int)blockIdx.y;
    if ((unsigned)oh >= (unsigned)GH) return;          // uniform

    __shared__ __align__(16) char smem[17408];
    bf16_t* sAh = (bf16_t*)smem;           // [8 g][66 w][8 bf16] = 8448 B
    bf16_t* sAl = (bf16_t*)(smem + 8448);  // 8448 B
    float*  sOut = (float*)smem;           // [64 w][68] fp32 = 17408 B (overlay)

    int t = threadIdx.x;
    int lane = t & 63, wv = t >> 6;
    int wl = lane & 15, kg = lane >> 4;
    int mh = wv >> 1, cth = wv & 1;
    int w0 = (int)blockIdx.x * 64;
    int od = (int)blockIdx.z;

    f32x4 acc[2][2];
    #pragma unroll
    for (int a = 0; a < 2; ++a)
        #pragma unroll
        for (int b = 0; b < 2; ++b) acc[a][b] = (f32x4){0.f, 0.f, 0.f, 0.f};

    const bf16x8* WH = (const bf16x8*)wph;
    const bf16x8* WL = (const bf16x8*)wpl;

    for (int kd = 0; kd < 3; ++kd) {
        int dp = od*d_stride + kd - d_pad;
        if (dp < 0 || dp >= D_in) continue;            // uniform
        const float* sdb = src + dp*src_dpitch;
        for (int kh = 0; kh < 3; ++kh) {
            int hp = oh + kh - 1;
            bool vh = ((unsigned)hp < (unsigned)GH);
            const float* srow = sdb + (long)(hp - src_h0) * (GW*64);
            __syncthreads();                           // prior phase reads done
            for (int c = t; c < 528; c += 256) {
                int g = c & 7, w = c >> 3;
                int gw = w0 - 1 + w;
                f32x4 v0 = {0.f,0.f,0.f,0.f}, v1 = {0.f,0.f,0.f,0.f};
                if (vh && (unsigned)gw < (unsigned)GW) {
                    const float* p = srow + (long)gw*64 + g*8;
                    v0 = *(const f32x4*)p;
                    v1 = *(const f32x4*)(p + 4);
                    f32x4 ga = *(const f32x4*)(gact + g*8);
                    f32x4 gb = *(const f32x4*)(gact + g*8 + 4);
                    f32x4 ba = *(const f32x4*)(gact + 64 + g*8);
                    f32x4 bb = *(const f32x4*)(gact + 64 + g*8 + 4);
                    #pragma unroll
                    for (int e = 0; e < 4; ++e) {
                        v0[e] = fmaxf(v0[e]*ga[e] + ba[e], 0.f);
                        v1[e] = fmaxf(v1[e]*gb[e] + bb[e], 0.f);
                    }
                }
                bf16x8 hi, lo;
                #pragma unroll
                for (int e = 0; e < 4; ++e) {
                    bf16_t h0 = (bf16_t)v0[e];
                    hi[e] = h0; lo[e] = (bf16_t)(v0[e] - (float)h0);
                    bf16_t h1 = (bf16_t)v1[e];
                    hi[4+e] = h1; lo[4+e] = (bf16_t)(v1[e] - (float)h1);
                }
                *(bf16x8*)&sAh[(g*66 + w)*8] = hi;
                *(bf16x8*)&sAl[(g*66 + w)*8] = lo;
            }
            __syncthreads();
            #pragma unroll
            for (int h = 0; h < 2; ++h) {
                #pragma unroll
                for (int kw = 0; kw < 3; ++kw) {
                    int s = ((kd*3 + kh)*3 + kw)*2 + h;
                    long fb = (long)(s*4 + cth*2)*64 + lane;
                    bf16x8 B0h = WH[fb],      B0l = WL[fb];
                    bf16x8 B1h = WH[fb + 64], B1l = WL[fb + 64];
                    #pragma unroll
                    for (int mt = 0; mt < 2; ++mt) {
                        int ai = ((h*4 + kg)*66 + (mh*2 + mt)*16 + kw + wl)*8;
                        bf16x8 Ah = *(const bf16x8*)&sAh[ai];
                        bf16x8 Al = *(const bf16x8*)&sAl[ai];
                        acc[mt][0] = __builtin_amdgcn_mfma_f32_16x16x32_bf16(Ah, B0h, acc[mt][0], 0, 0, 0);
                        acc[mt][0] = __builtin_amdgcn_mfma_f32_16x16x32_bf16(Ah, B0l, acc[mt][0], 0, 0, 0);
                        acc[mt][0] = __builtin_amdgcn_mfma_f32_16x16x32_bf16(Al, B0h, acc[mt][0], 0, 0, 0);
                        acc[mt][1] = __builtin_amdgcn_mfma_f32_16x16x32_bf16(Ah, B1h, acc[mt][1], 0, 0, 0);
                        acc[mt][1] = __builtin_amdgcn_mfma_f32_16x16x32_bf16(Ah, B1l, acc[mt][1], 0, 0, 0);
                        acc[mt][1] = __builtin_amdgcn_mfma_f32_16x16x32_bf16(Al, B1h, acc[mt][1], 0, 0, 0);
                    }
                }
            }
        }
    }

    // ---- epilogue ----
    float so[2], bo[2];
    #pragma unroll
    for (int ct = 0; ct < 2; ++ct) {
        int co = (cth*2 + ct)*16 + wl;
        so[ct] = gout[co]*BNC; bo[ct] = bout[co];
    }
    if (sW == 1) {
        #pragma unroll
        for (int mt = 0; mt < 2; ++mt) {
            int ow = w0 + (mh*2 + mt)*16 + kg*4;
            if (ow < GW) {
                #pragma unroll
                for (int ct = 0; ct < 2; ++ct) {
                    int co = (cth*2 + ct)*16 + wl;
                    f32x4 r;
                    #pragma unroll
                    for (int e = 0; e < 4; ++e)
                        r[e] = fmaxf(acc[mt][ct][e]*so[ct] + bo[ct], 0.f);
                    *(f32x4*)&dst[(long)co*sC + (long)od*sD + (long)(oh - dst_h0)*sH + ow] = r;
                }
            }
        }
    } else {
        __syncthreads();      // done reading sA (overlay!)
        #pragma unroll
        for (int mt = 0; mt < 2; ++mt)
            #pragma unroll
            for (int ct = 0; ct < 2; ++ct) {
                int co = (cth*2 + ct)*16 + wl;
                #pragma unroll
                for (int e = 0; e < 4; ++e) {
                    int owl = (mh*2 + mt)*16 + kg*4 + e;
                    sOut[owl*68 + co] = fmaxf(acc[mt][ct][e]*so[ct] + bo[ct], 0.f);
                }
            }
        __syncthreads();
        for (int f = t; f < 1024; f += 256) {
            int w = f >> 4, c4 = f & 15;
            if (w0 + w < GW) {
                float4 v = *(const float4*)&sOut[w*68 + c4*4];
                *(float4*)&dst[(long)od*sD + (long)(oh - dst_h0)*sH + (long)(w0 + w)*64 + c4*4] = v;
            }
        }
    }
}

// ---------------------------------------------------------------------------
extern "C" void kernel_launch(void* const* d_in, const int* in_sizes, int n_in,
                              void* d_out, int out_size, void* d_ws, size_t ws_size,
                              hipStream_t stream)
{
    const float* feats = (const float*)d_in[0];
    const int*   nvox  = (const int*)d_in[1];
    const int*   coors = (const int*)d_in[2];
    const float* w1  = (const float*)d_in[4];
    const float* g1  = (const float*)d_in[5];
    const float* b1  = (const float*)d_in[6];
    const float* w2  = (const float*)d_in[7];
    const float* g2  = (const float*)d_in[8];
    const float* b2  = (const float*)d_in[9];
    const float* wl  = (const float*)d_in[10];
    const float* gl  = (const float*)d_in[11];
    const float* bl  = (const float*)d_in[12];
    const float* wc1 = (const float*)d_in[13];
    const float* gc1 = (const float*)d_in[14];
    const float* bc1 = (const float*)d_in[15];
    const float* wc2 = (const float*)d_in[16];
    const float* gc2 = (const float*)d_in[17];
    const float* bc2 = (const float*)d_in[18];
    const float* wc3 = (const float*)d_in[19];
    const float* gc3 = (const float*)d_in[20];
    const float* bc3 = (const float*)d_in[21];

    int N = in_sizes[1];            // 20000 voxels

    auto al = [](size_t b) { return (b + 255) & ~(size_t)255; };

    size_t winB = al((size_t)10*GH*GW*4);
    size_t voxB = al((size_t)N*128*4);
    size_t w1B  = al((size_t)27*128*64*4);
    size_t wlB  = al((size_t)128*128*4);
    size_t wpB  = al((size_t)13824*8*2);   // one packed bf16 weight buffer
    int NS = 16;
    const int cand[5] = {1, 2, 4, 8, 16};
    for (int k = 0; k < 5; ++k) {
        int ns = cand[k], sh = 400/ns, ar = sh + 4, xr = sh + 2;
        size_t tot = al((size_t)5*ar*GW*64*4) + al((size_t)3*xr*GW*64*4)
                   + winB + voxB + w1B + wlB + 4*wpB + 4096;
        if (tot + (1<<16) <= ws_size) { NS = ns; break; }
    }
    int SH = 400/NS, AR = SH + 4, XR = SH + 2;

    char* ws = (char*)d_ws;
    size_t off = 0;
    auto alloc = [&](size_t bytes) -> void* {
        void* p = ws + off; off += al(bytes); return p;
    };
    size_t accB = (size_t)5*AR*GW*64*4;
    size_t actB = (size_t)3*XR*GW*64*4;
    float*  accS   = (float*)alloc(accB);
    float*  actS   = (float*)alloc(actB);
    int*    winner = (int*)alloc((size_t)10*GH*GW*4);
    float*  voxw   = (float*)alloc((size_t)N*128*4);
    float*  wt1    = (float*)alloc((size_t)27*128*64*4);
    float*  wtl    = (float*)alloc((size_t)128*128*4);
    bf16_t* wp2h   = (bf16_t*)alloc(wpB);
    bf16_t* wp2l   = (bf16_t*)alloc(wpB);
    bf16_t* wp3h   = (bf16_t*)alloc(wpB);
    bf16_t* wp3l   = (bf16_t*)alloc(wpB);
    float*  gact   = (float*)alloc(256*4);

    hipMemsetAsync(winner, 0xFF, (size_t)10*GH*GW*4, stream);

    k_tr_w<<<(27*128*64 + 255)/256, 256, 0, stream>>>(wc1, wt1, 128, 64);
    k_tr_lin<<<64, 256, 0, stream>>>(wl, wtl);
    k_packw<<<54, 256, 0, stream>>>(wc2, wp2h, wp2l);
    k_packw<<<54, 256, 0, stream>>>(wc3, wp3h, wp3l);
    k_prep<<<1, 256, 0, stream>>>(gc1, bc1, gact);

    k_winner<<<(N + 255)/256, 256, 0, stream>>>(coors, winner, N);
    k_vfe<<<N, 128, 0, stream>>>(feats, nvox, w1, g1, b1, w2, g2, b2, wtl, gl, bl, voxw);

    for (int s = 0; s < NS; ++s) {
        // conv1 gather: fills ALL rows of accS (incl. zeros) -> no memset
        k_gat1<<<dim3(11, AR, 5), 256, 0, stream>>>(
            (const float4*)voxw, winner, (const float4*)wt1,
            accS, s*SH - 2, AR);
        // conv2 (MFMA): src accS raw (fuse bn1+relu via gact), dst actS
        k_convm<<<dim3(6, SH + 2, 3), 256, 0, stream>>>(
            accS, s*SH - 2, (long)AR*GW*64,
            actS, s*SH - 1, 1L, (long)XR*GW*64, (long)GW*64, 64L,
            wp2h, wp2l, gact, gc2, bc2,
            5, 1, 0, s*SH - 1);
        // conv3 (MFMA): src actS activated (identity gact+128); dst d_out
        k_convm<<<dim3(6, SH, 2), 256, 0, stream>>>(
            actS, s*SH - 1, (long)XR*GW*64,
            (float*)d_out, 0, (long)2*GH*GW, (long)GH*GW, (long)GW, 1L,
            wp3h, wp3l, gact + 128, gc3, bc3,
            3, 2, 1, s*SH);
    }
}

// Round 9
// 1015.437 us; speedup vs baseline: 1.4784x; 1.4784x over previous
//
#include <hip/hip_runtime.h>
#include <hip/hip_bf16.h>

#define BNC 0.99950037f   // 1/sqrt(1+1e-3), BN eval scale factor
#define GH 400
#define GW 352

typedef __bf16 bf16_t;
typedef __bf16 bf16x8 __attribute__((ext_vector_type(8)));
typedef float f32x4 __attribute__((ext_vector_type(4)));

// ---------------------------------------------------------------------------
// Winner grid: last voxel index wins for duplicate cells (matches np fancy-set)
// ---------------------------------------------------------------------------
__global__ void k_winner(const int* __restrict__ coors, int* __restrict__ winner, int N) {
    int i = blockIdx.x * 256 + threadIdx.x;
    if (i >= N) return;
    int d = coors[i*4+1], h = coors[i*4+2], w = coors[i*4+3];
    atomicMax(&winner[(d*GH + h)*GW + w], i);
}

// ---------------------------------------------------------------------------
// Weight transpose for conv1/gather: OIDHW -> [tap][ci4][co][4]
// ---------------------------------------------------------------------------
__global__ void k_tr_w(const float* __restrict__ w, float* __restrict__ wt, int CI, int CO) {
    int idx = blockIdx.x * 256 + threadIdx.x;
    int total = 27 * CI * CO;
    if (idx >= total) return;
    int j   = idx & 3;
    int t1  = idx >> 2;
    int co  = t1 % CO;
    int t2  = t1 / CO;
    int ci4 = t2 % (CI/4);
    int tap = t2 / (CI/4);
    int ci  = ci4*4 + j;
    wt[idx] = w[(co*CI + ci)*27 + tap];
}

// Linear-layer weight transpose: wl[u][c] -> WT[c][u]
__global__ void k_tr_lin(const float* __restrict__ wl, float* __restrict__ WT) {
    int idx = blockIdx.x * 256 + threadIdx.x;
    if (idx >= 16384) return;
    int u = idx & 127, c = idx >> 7;
    WT[c*128 + u] = wl[u*128 + c];
}

// Input-activation table for convs: [0:64) gc1*BNC, [64:128) bc1,
// [128:192) 1.0, [192:256) 0.0 (identity block for conv3)
__global__ void k_prep(const float* __restrict__ g, const float* __restrict__ b,
                       float* __restrict__ out) {
    int i = threadIdx.x;
    if (i < 64)       out[i] = g[i] * BNC;
    else if (i < 128) out[i] = b[i-64];
    else if (i < 192) out[i] = 1.f;
    else              out[i] = 0.f;
}

// ---------------------------------------------------------------------------
// Pack 64x64x27 conv weights (OIDHW fp32) into MFMA B-fragment order, split
// into hi/lo bf16. Frag index fb = (s*4 + ct)*64 + lane, s = tap*2 + h.
// Lane l of B[k][n]: n(co) = ct*16 + (l&15), k(ci) = h*32 + (l>>4)*8 + j.
// ---------------------------------------------------------------------------
__global__ void k_packw(const float* __restrict__ w, bf16_t* __restrict__ wh,
                        bf16_t* __restrict__ wlo) {
    int i = blockIdx.x * 256 + threadIdx.x;    // over 54*4*64 = 13824 frag-lanes
    if (i >= 13824) return;
    int lane = i & 63, ct = (i >> 6) & 3, s = i >> 8;
    int tap = s >> 1, h = s & 1;
    int kg = lane >> 4, wl = lane & 15;
    int co = ct*16 + wl;
    #pragma unroll
    for (int j = 0; j < 8; ++j) {
        int ci = h*32 + kg*8 + j;
        float v = w[(co*64 + ci)*27 + tap];
        bf16_t hi = (bf16_t)v;
        wh[(long)i*8 + j]  = hi;
        wlo[(long)i*8 + j] = (bf16_t)(v - (float)hi);
    }
}

// ---------------------------------------------------------------------------
// VFE: one block (128 thr) per voxel. Agg-split form (unchanged from r7).
// ---------------------------------------------------------------------------
__global__ __launch_bounds__(128) void k_vfe(
    const float* __restrict__ feats, const int* __restrict__ nvox,
    const float* __restrict__ w1, const float* __restrict__ g1g, const float* __restrict__ b1g,
    const float* __restrict__ w2g, const float* __restrict__ g2g, const float* __restrict__ b2g,
    const float* __restrict__ WT, const float* __restrict__ glg, const float* __restrict__ blg,
    float* __restrict__ voxelwise)
{
    __shared__ float F[35*8];
    __shared__ float W1s[16*8];
    __shared__ float SG1[16], SB1[16];
    __shared__ float X1[35*20];
    __shared__ float X2[35*68];
    __shared__ float RED[8*128];
    __shared__ float AGG1[16];
    __shared__ float AGG2[64];
    __shared__ float Y2B[64];
    __shared__ float YB[128];
    __shared__ float MEANS[3];

    int tid = threadIdx.x;
    int vox = blockIdx.x;
    int nv  = nvox[vox];

    const float* fsrc = feats + (long)vox * 140;
    for (int idx = tid; idx < 140; idx += 128) { int t = idx>>2, c = idx&3; F[t*8+c] = fsrc[idx]; }
    if (tid < 35) F[tid*8+7] = 0.f;
    if (tid < 112) { int u = tid/7, c = tid - u*7; W1s[u*8+c] = w1[tid]; }
    if (tid < 16)  { W1s[tid*8+7] = 0.f; SG1[tid] = g1g[tid]*BNC; SB1[tid] = b1g[tid]; }
    __syncthreads();

    if (tid < 3) {
        float s = 0.f;
        for (int t = 0; t < 35; ++t) s += F[t*8 + tid];
        MEANS[tid] = s / (float)nv;
    }
    __syncthreads();
    for (int idx = tid; idx < 105; idx += 128) { int t = idx/3, c = idx - t*3; F[t*8+4+c] = F[t*8+c] - MEANS[c]; }
    __syncthreads();

    {
        const float4* Ff4  = (const float4*)F;
        const float4* W1f4 = (const float4*)W1s;
        for (int idx = tid; idx < 560; idx += 128) {
            int t = idx >> 4, u = idx & 15;
            float4 a0 = Ff4[t*2], a1 = Ff4[t*2+1];
            float4 b0 = W1f4[u*2], b1v = W1f4[u*2+1];
            float a = a0.x*b0.x + a0.y*b0.y + a0.z*b0.z + a0.w*b0.w
                    + a1.x*b1v.x + a1.y*b1v.y + a1.z*b1v.z + a1.w*b1v.w;
            X1[t*20+u] = fmaxf(a*SG1[u] + SB1[u], 0.f);
        }
    }
    __syncthreads();
    if (tid < 16) {
        float m = 0.f;
        for (int t = 0; t < 35; ++t) m = fmaxf(m, X1[t*20+tid]);
        AGG1[tid] = m;
    }
    __syncthreads();
    if (tid < 64) {
        const float4* wsrc = (const float4*)(w2g + tid*32 + 16);
        const float4* A1f4 = (const float4*)AGG1;
        float a = 0.f;
        #pragma unroll
        for (int q = 0; q < 4; ++q) {
            float4 w4 = wsrc[q], x4 = A1f4[q];
            a += x4.x*w4.x + x4.y*w4.y + x4.z*w4.z + x4.w*w4.w;
        }
        Y2B[tid] = a;
    }
    __syncthreads();

    {
        int u = tid & 63, tg = tid >> 6;
        float w2r[16];
        const float4* wsrc = (const float4*)(w2g + u*32);
        #pragma unroll
        for (int q = 0; q < 4; ++q) {
            float4 w4 = wsrc[q];
            w2r[q*4] = w4.x; w2r[q*4+1] = w4.y; w2r[q*4+2] = w4.z; w2r[q*4+3] = w4.w;
        }
        float su = g2g[u]*BNC, bu = b2g[u];
        float yb2 = Y2B[u];
        float lm = (nv < 35) ? fmaxf(bu, 0.f) : 0.f;
        for (int t = tg; t < nv; t += 2) {
            const float4* xr = (const float4*)(X1 + t*20);
            float a = yb2;
            #pragma unroll
            for (int q = 0; q < 4; ++q) {
                float4 x4 = xr[q];
                a += x4.x*w2r[q*4] + x4.y*w2r[q*4+1] + x4.z*w2r[q*4+2] + x4.w*w2r[q*4+3];
            }
            float h = fmaxf(a*su + bu, 0.f);
            X2[t*68 + u] = h;
            lm = fmaxf(lm, h);
        }
        RED[tg*64 + u] = lm;
    }
    __syncthreads();
    if (tid < 64) AGG2[tid] = fmaxf(RED[tid], RED[64+tid]);
    __syncthreads();
    {
        float a = 0.f;
        for (int c = 0; c < 64; ++c) a = fmaf(AGG2[c], WT[(64 + c)*128 + tid], a);
        YB[tid] = a;
    }
    __syncthreads();

    {
        int ug = tid & 15, tg4 = tid >> 4;
        int u0 = ug * 8;
        int kmax = (nv > tg4) ? ((nv - tg4 + 7) >> 3) : 0;
        float acc[5][8];
        #pragma unroll
        for (int k = 0; k < 5; ++k)
            #pragma unroll
            for (int j = 0; j < 8; ++j) acc[k][j] = 0.f;

        const float4* X2f4 = (const float4*)X2;
        const float4* WTf4 = (const float4*)WT;
        for (int c4 = 0; c4 < 16; ++c4) {
            float4 wv[8];
            #pragma unroll
            for (int cc = 0; cc < 4; ++cc) {
                wv[cc*2]   = WTf4[(c4*4+cc)*32 + ug*2];
                wv[cc*2+1] = WTf4[(c4*4+cc)*32 + ug*2 + 1];
            }
            #pragma unroll
            for (int k = 0; k < 5; ++k) {
                if (k < kmax) {
                    int t = tg4 + (k << 3);
                    float4 x4 = X2f4[t*17 + c4];
                    #pragma unroll
                    for (int cc = 0; cc < 4; ++cc) {
                        float xs = (cc == 0) ? x4.x : (cc == 1) ? x4.y : (cc == 2) ? x4.z : x4.w;
                        acc[k][0] = fmaf(xs, wv[cc*2].x,   acc[k][0]);
                        acc[k][1] = fmaf(xs, wv[cc*2].y,   acc[k][1]);
                        acc[k][2] = fmaf(xs, wv[cc*2].z,   acc[k][2]);
                        acc[k][3] = fmaf(xs, wv[cc*2].w,   acc[k][3]);
                        acc[k][4] = fmaf(xs, wv[cc*2+1].x, acc[k][4]);
                        acc[k][5] = fmaf(xs, wv[cc*2+1].y, acc[k][5]);
                        acc[k][6] = fmaf(xs, wv[cc*2+1].z, acc[k][6]);
                        acc[k][7] = fmaf(xs, wv[cc*2+1].w, acc[k][7]);
                    }
                }
            }
        }
        float4 g0 = *(const float4*)(glg + u0), g1v = *(const float4*)(glg + u0 + 4);
        float4 b0 = *(const float4*)(blg + u0), b1v = *(const float4*)(blg + u0 + 4);
        float4 y0 = *(const float4*)(YB + u0),  y1v = *(const float4*)(YB + u0 + 4);
        float sg[8] = {g0.x*BNC, g0.y*BNC, g0.z*BNC, g0.w*BNC,
                       g1v.x*BNC, g1v.y*BNC, g1v.z*BNC, g1v.w*BNC};
        float sb[8] = {b0.x, b0.y, b0.z, b0.w, b1v.x, b1v.y, b1v.z, b1v.w};
        float yv[8] = {y0.x, y0.y, y0.z, y0.w, y1v.x, y1v.y, y1v.z, y1v.w};
        float m[8];
        #pragma unroll
        for (int j = 0; j < 8; ++j) m[j] = 0.f;
        #pragma unroll
        for (int k = 0; k < 5; ++k) {
            if (k < kmax) {
                #pragma unroll
                for (int j = 0; j < 8; ++j)
                    m[j] = fmaxf(m[j], fmaxf((acc[k][j] + yv[j])*sg[j] + sb[j], 0.f));
            }
        }
        #pragma unroll
        for (int j = 0; j < 8; ++j) RED[tg4*128 + u0 + j] = m[j];
    }
    __syncthreads();
    {
        float m = RED[tid];
        #pragma unroll
        for (int r = 1; r < 8; ++r) m = fmaxf(m, RED[r*128 + tid]);
        voxelwise[(long)vox*128 + tid] = m;
    }
}

// ---------------------------------------------------------------------------
// conv1 gather v2: worklist form. A block's 306-cell winner window averages
// ~4 occupied voxels (1.4% grid occupancy). Build an LDS worklist of valid
// (voxel,kd,kh,x) entries, stage those voxels' features into LDS in chunks
// of 32, then each wave processes entries hitting its 8 output cells with
// k_scat's efficient inner loop: weight float4 loaded once per c4 (coalesced,
// L1-hot), features broadcast from LDS. Atomic-free full-coverage stores.
// ---------------------------------------------------------------------------
__global__ __launch_bounds__(256) void k_gat1(
    const float4* __restrict__ voxf4, const int* __restrict__ winner,
    const float4* __restrict__ Wt1, float* __restrict__ accS,
    int h_lo, int AR)
{
    int r  = blockIdx.y;               // row within strip accumulator
    int oh = h_lo + r;
    if ((unsigned)oh >= (unsigned)GH) return;   // conv2 never reads such rows
    int doo = blockIdx.z;
    int w0  = blockIdx.x * 32;

    __shared__ int sList[306];
    __shared__ int sCnt;
    __shared__ float4 sF[32][32];      // 16 KB feature chunk

    int t = threadIdx.x;
    if (t == 0) sCnt = 0;
    __syncthreads();
    // window cell (kd,kh,x): input (dp,hp,wp) = (2*doo+kd-1, oh+kh-1, w0-1+x)
    for (int idx = t; idx < 306; idx += 256) {
        int x = idx % 34, q = idx / 34;
        int kd = q / 3, kh = q - kd*3;
        int dp = doo*2 + kd - 1;
        int hp = oh + kh - 1;
        int wp = w0 - 1 + x;
        if ((unsigned)dp < 10u && (unsigned)hp < (unsigned)GH && (unsigned)wp < (unsigned)GW) {
            int v = winner[(dp*GH + hp)*GW + wp];
            if (v >= 0) {
                int p = atomicAdd(&sCnt, 1);
                sList[p] = (v << 10) | (kd << 8) | (kh << 6) | x;
            }
        }
    }
    __syncthreads();
    int cnt = sCnt;

    int co = t & 63, wv = t >> 6;
    int ibase = wv*8;                  // this wave's 8 output cells
    float acc[8];
    #pragma unroll
    for (int i = 0; i < 8; ++i) acc[i] = 0.f;

    for (int c0 = 0; c0 < cnt; c0 += 32) {
        int nch = min(32, cnt - c0);
        __syncthreads();               // previous chunk's sF readers done
        for (int idx = t; idx < nch*32; idx += 256) {
            int slot = idx >> 5, c = idx & 31;
            int widx = sList[c0 + slot] >> 10;
            sF[slot][c] = voxf4[(long)widx*32 + c];
        }
        __syncthreads();
        for (int e = 0; e < nch; ++e) {
            int ent = sList[c0 + e];
            int x = ent & 63, kh = (ent >> 6) & 3, kd = (ent >> 8) & 3;
            #pragma unroll
            for (int kw = 0; kw < 3; ++kw) {
                int i = x - kw;        // output cell this (entry,kw) feeds
                if (i >= ibase && i < ibase + 8) {      // wave-uniform
                    const float4* wb = Wt1 + (long)(kd*9 + kh*3 + kw)*2048 + co;
                    float a = 0.f;
                    #pragma unroll 4
                    for (int c4 = 0; c4 < 32; ++c4) {
                        float4 wq = wb[c4*64];
                        float4 f4 = sF[e][c4];
                        a += f4.x*wq.x + f4.y*wq.y + f4.z*wq.z + f4.w*wq.w;
                    }
                    int j = i - ibase;
                    #pragma unroll
                    for (int j8 = 0; j8 < 8; ++j8)      // static acc indexing
                        if (j8 == j) acc[j8] += a;
                }
            }
        }
    }

    long rowb = ((long)doo*AR + r)*GW + w0;
    #pragma unroll
    for (int i = 0; i < 8; ++i)
        accS[(rowb + ibase + i)*64 + co] = acc[i];
}

// ---------------------------------------------------------------------------
// Dense conv3d via MFMA 16x16x32 bf16, 3-product hi/lo split (unchanged).
// ---------------------------------------------------------------------------
__global__ __launch_bounds__(256) void k_convm(
    const float* __restrict__ src, int src_h0, long src_dpitch,
    float* __restrict__ dst, int dst_h0, long sC, long sD, long sH, long sW,
    const bf16_t* __restrict__ wph, const bf16_t* __restrict__ wpl,
    const float* __restrict__ gact,
    const float* __restrict__ gout, const float* __restrict__ bout,
    int D_in, int d_stride, int d_pad, int y0)
{
    int oh = y0 + (int)blockIdx.y;
    if ((unsigned)oh >= (unsigned)GH) return;          // uniform

    __shared__ __align__(16) char smem[17408];
    bf16_t* sAh = (bf16_t*)smem;           // [8 g][66 w][8 bf16] = 8448 B
    bf16_t* sAl = (bf16_t*)(smem + 8448);  // 8448 B
    float*  sOut = (float*)smem;           // [64 w][68] fp32 = 17408 B (overlay)

    int t = threadIdx.x;
    int lane = t & 63, wv = t >> 6;
    int wl = lane & 15, kg = lane >> 4;
    int mh = wv >> 1, cth = wv & 1;
    int w0 = (int)blockIdx.x * 64;
    int od = (int)blockIdx.z;

    f32x4 acc[2][2];
    #pragma unroll
    for (int a = 0; a < 2; ++a)
        #pragma unroll
        for (int b = 0; b < 2; ++b) acc[a][b] = (f32x4){0.f, 0.f, 0.f, 0.f};

    const bf16x8* WH = (const bf16x8*)wph;
    const bf16x8* WL = (const bf16x8*)wpl;

    for (int kd = 0; kd < 3; ++kd) {
        int dp = od*d_stride + kd - d_pad;
        if (dp < 0 || dp >= D_in) continue;            // uniform
        const float* sdb = src + dp*src_dpitch;
        for (int kh = 0; kh < 3; ++kh) {
            int hp = oh + kh - 1;
            bool vh = ((unsigned)hp < (unsigned)GH);
            const float* srow = sdb + (long)(hp - src_h0) * (GW*64);
            __syncthreads();                           // prior phase reads done
            for (int c = t; c < 528; c += 256) {
                int g = c & 7, w = c >> 3;
                int gw = w0 - 1 + w;
                f32x4 v0 = {0.f,0.f,0.f,0.f}, v1 = {0.f,0.f,0.f,0.f};
                if (vh && (unsigned)gw < (unsigned)GW) {
                    const float* p = srow + (long)gw*64 + g*8;
                    v0 = *(const f32x4*)p;
                    v1 = *(const f32x4*)(p + 4);
                    f32x4 ga = *(const f32x4*)(gact + g*8);
                    f32x4 gb = *(const f32x4*)(gact + g*8 + 4);
                    f32x4 ba = *(const f32x4*)(gact + 64 + g*8);
                    f32x4 bb = *(const f32x4*)(gact + 64 + g*8 + 4);
                    #pragma unroll
                    for (int e = 0; e < 4; ++e) {
                        v0[e] = fmaxf(v0[e]*ga[e] + ba[e], 0.f);
                        v1[e] = fmaxf(v1[e]*gb[e] + bb[e], 0.f);
                    }
                }
                bf16x8 hi, lo;
                #pragma unroll
                for (int e = 0; e < 4; ++e) {
                    bf16_t h0 = (bf16_t)v0[e];
                    hi[e] = h0; lo[e] = (bf16_t)(v0[e] - (float)h0);
                    bf16_t h1 = (bf16_t)v1[e];
                    hi[4+e] = h1; lo[4+e] = (bf16_t)(v1[e] - (float)h1);
                }
                *(bf16x8*)&sAh[(g*66 + w)*8] = hi;
                *(bf16x8*)&sAl[(g*66 + w)*8] = lo;
            }
            __syncthreads();
            #pragma unroll
            for (int h = 0; h < 2; ++h) {
                #pragma unroll
                for (int kw = 0; kw < 3; ++kw) {
                    int s = ((kd*3 + kh)*3 + kw)*2 + h;
                    long fb = (long)(s*4 + cth*2)*64 + lane;
                    bf16x8 B0h = WH[fb],      B0l = WL[fb];
                    bf16x8 B1h = WH[fb + 64], B1l = WL[fb + 64];
                    #pragma unroll
                    for (int mt = 0; mt < 2; ++mt) {
                        int ai = ((h*4 + kg)*66 + (mh*2 + mt)*16 + kw + wl)*8;
                        bf16x8 Ah = *(const bf16x8*)&sAh[ai];
                        bf16x8 Al = *(const bf16x8*)&sAl[ai];
                        acc[mt][0] = __builtin_amdgcn_mfma_f32_16x16x32_bf16(Ah, B0h, acc[mt][0], 0, 0, 0);
                        acc[mt][0] = __builtin_amdgcn_mfma_f32_16x16x32_bf16(Ah, B0l, acc[mt][0], 0, 0, 0);
                        acc[mt][0] = __builtin_amdgcn_mfma_f32_16x16x32_bf16(Al, B0h, acc[mt][0], 0, 0, 0);
                        acc[mt][1] = __builtin_amdgcn_mfma_f32_16x16x32_bf16(Ah, B1h, acc[mt][1], 0, 0, 0);
                        acc[mt][1] = __builtin_amdgcn_mfma_f32_16x16x32_bf16(Ah, B1l, acc[mt][1], 0, 0, 0);
                        acc[mt][1] = __builtin_amdgcn_mfma_f32_16x16x32_bf16(Al, B1h, acc[mt][1], 0, 0, 0);
                    }
                }
            }
        }
    }

    // ---- epilogue ----
    float so[2], bo[2];
    #pragma unroll
    for (int ct = 0; ct < 2; ++ct) {
        int co = (cth*2 + ct)*16 + wl;
        so[ct] = gout[co]*BNC; bo[ct] = bout[co];
    }
    if (sW == 1) {
        #pragma unroll
        for (int mt = 0; mt < 2; ++mt) {
            int ow = w0 + (mh*2 + mt)*16 + kg*4;
            if (ow < GW) {
                #pragma unroll
                for (int ct = 0; ct < 2; ++ct) {
                    int co = (cth*2 + ct)*16 + wl;
                    f32x4 r;
                    #pragma unroll
                    for (int e = 0; e < 4; ++e)
                        r[e] = fmaxf(acc[mt][ct][e]*so[ct] + bo[ct], 0.f);
                    *(f32x4*)&dst[(long)co*sC + (long)od*sD + (long)(oh - dst_h0)*sH + ow] = r;
                }
            }
        }
    } else {
        __syncthreads();      // done reading sA (overlay!)
        #pragma unroll
        for (int mt = 0; mt < 2; ++mt)
            #pragma unroll
            for (int ct = 0; ct < 2; ++ct) {
                int co = (cth*2 + ct)*16 + wl;
                #pragma unroll
                for (int e = 0; e < 4; ++e) {
                    int owl = (mh*2 + mt)*16 + kg*4 + e;
                    sOut[owl*68 + co] = fmaxf(acc[mt][ct][e]*so[ct] + bo[ct], 0.f);
                }
            }
        __syncthreads();
        for (int f = t; f < 1024; f += 256) {
            int w = f >> 4, c4 = f & 15;
            if (w0 + w < GW) {
                float4 v = *(const float4*)&sOut[w*68 + c4*4];
                *(float4*)&dst[(long)od*sD + (long)(oh - dst_h0)*sH + (long)(w0 + w)*64 + c4*4] = v;
            }
        }
    }
}

// ---------------------------------------------------------------------------
extern "C" void kernel_launch(void* const* d_in, const int* in_sizes, int n_in,
                              void* d_out, int out_size, void* d_ws, size_t ws_size,
                              hipStream_t stream)
{
    const float* feats = (const float*)d_in[0];
    const int*   nvox  = (const int*)d_in[1];
    const int*   coors = (const int*)d_in[2];
    const float* w1  = (const float*)d_in[4];
    const float* g1  = (const float*)d_in[5];
    const float* b1  = (const float*)d_in[6];
    const float* w2  = (const float*)d_in[7];
    const float* g2  = (const float*)d_in[8];
    const float* b2  = (const float*)d_in[9];
    const float* wl  = (const float*)d_in[10];
    const float* gl  = (const float*)d_in[11];
    const float* bl  = (const float*)d_in[12];
    const float* wc1 = (const float*)d_in[13];
    const float* gc1 = (const float*)d_in[14];
    const float* bc1 = (const float*)d_in[15];
    const float* wc2 = (const float*)d_in[16];
    const float* gc2 = (const float*)d_in[17];
    const float* bc2 = (const float*)d_in[18];
    const float* wc3 = (const float*)d_in[19];
    const float* gc3 = (const float*)d_in[20];
    const float* bc3 = (const float*)d_in[21];

    int N = in_sizes[1];            // 20000 voxels

    auto al = [](size_t b) { return (b + 255) & ~(size_t)255; };

    size_t winB = al((size_t)10*GH*GW*4);
    size_t voxB = al((size_t)N*128*4);
    size_t w1B  = al((size_t)27*128*64*4);
    size_t wlB  = al((size_t)128*128*4);
    size_t wpB  = al((size_t)13824*8*2);   // one packed bf16 weight buffer
    int NS = 20;
    const int cand[8] = {1, 2, 4, 5, 8, 10, 16, 20};
    for (int k = 0; k < 8; ++k) {
        int ns = cand[k], sh = 400/ns, ar = sh + 4, xr = sh + 2;
        size_t tot = al((size_t)5*ar*GW*64*4) + al((size_t)3*xr*GW*64*4)
                   + winB + voxB + w1B + wlB + 4*wpB + 4096;
        if (tot + (1<<16) <= ws_size) { NS = ns; break; }
    }
    int SH = 400/NS, AR = SH + 4, XR = SH + 2;

    char* ws = (char*)d_ws;
    size_t off = 0;
    auto alloc = [&](size_t bytes) -> void* {
        void* p = ws + off; off += al(bytes); return p;
    };
    size_t accB = (size_t)5*AR*GW*64*4;
    size_t actB = (size_t)3*XR*GW*64*4;
    float*  accS   = (float*)alloc(accB);
    float*  actS   = (float*)alloc(actB);
    int*    winner = (int*)alloc((size_t)10*GH*GW*4);
    float*  voxw   = (float*)alloc((size_t)N*128*4);
    float*  wt1    = (float*)alloc((size_t)27*128*64*4);
    float*  wtl    = (float*)alloc((size_t)128*128*4);
    bf16_t* wp2h   = (bf16_t*)alloc(wpB);
    bf16_t* wp2l   = (bf16_t*)alloc(wpB);
    bf16_t* wp3h   = (bf16_t*)alloc(wpB);
    bf16_t* wp3l   = (bf16_t*)alloc(wpB);
    float*  gact   = (float*)alloc(256*4);

    hipMemsetAsync(winner, 0xFF, (size_t)10*GH*GW*4, stream);

    k_tr_w<<<(27*128*64 + 255)/256, 256, 0, stream>>>(wc1, wt1, 128, 64);
    k_tr_lin<<<64, 256, 0, stream>>>(wl, wtl);
    k_packw<<<54, 256, 0, stream>>>(wc2, wp2h, wp2l);
    k_packw<<<54, 256, 0, stream>>>(wc3, wp3h, wp3l);
    k_prep<<<1, 256, 0, stream>>>(gc1, bc1, gact);

    k_winner<<<(N + 255)/256, 256, 0, stream>>>(coors, winner, N);
    k_vfe<<<N, 128, 0, stream>>>(feats, nvox, w1, g1, b1, w2, g2, b2, wtl, gl, bl, voxw);

    for (int s = 0; s < NS; ++s) {
        // conv1 gather: fills ALL rows of accS (incl. zeros) -> no memset
        k_gat1<<<dim3(11, AR, 5), 256, 0, stream>>>(
            (const float4*)voxw, winner, (const float4*)wt1,
            accS, s*SH - 2, AR);
        // conv2 (MFMA): src accS raw (fuse bn1+relu via gact), dst actS
        k_convm<<<dim3(6, SH + 2, 3), 256, 0, stream>>>(
            accS, s*SH - 2, (long)AR*GW*64,
            actS, s*SH - 1, 1L, (long)XR*GW*64, (long)GW*64, 64L,
            wp2h, wp2l, gact, gc2, bc2,
            5, 1, 0, s*SH - 1);
        // conv3 (MFMA): src actS activated (identity gact+128); dst d_out
        k_convm<<<dim3(6, SH, 2), 256, 0, stream>>>(
            actS, s*SH - 1, (long)XR*GW*64,
            (float*)d_out, 0, (long)2*GH*GW, (long)GH*GW, (long)GW, 1L,
            wp3h, wp3l, gact + 128, gc3, bc3,
            3, 2, 1, s*SH);
    }
}